// Round 8
// baseline (235.690 us; speedup 1.0000x reference)
//
#include <hip/hip_runtime.h>
#include <hip/hip_bf16.h>

#define N_SEG 64
#define N_P   164             // 82 landmarks * 2 coords
#define NSP   (N_SEG * N_P)   // 10496
#define ROW   1629            // 543 * 3 floats per frame
#define NC    40              // frame chunks (producers) per segment
#define NBLK  (N_SEG * NC)    // 2560 blocks

#define FIN_COLS   32
#define FIN_GROUPS 8
#define KC_PER_G   (NC / FIN_GROUPS)

__device__ __constant__ int LIPS[40] = {
    61, 185, 40, 39, 37, 0, 267, 269, 270, 409, 291, 146, 91, 181, 84, 17,
    314, 405, 321, 375, 78, 191, 80, 81, 82, 13, 312, 311, 310, 415, 95, 88,
    178, 87, 14, 317, 402, 318, 324, 308};

__device__ __forceinline__ int landmark_offset(int tid) {
    const int l = tid >> 1;
    const int c = tid & 1;
    int lm;
    if (l < 21)      lm = 468 + l;
    else if (l < 42) lm = 501 + l;           // 522 + (l-21)
    else             lm = LIPS[l - 42];
    return lm * 3 + c;
}

__device__ __forceinline__ void seg_bounds(int s, int T, int* lo, int* hi) {
    const float step = (float)(T - 1) / 64.0f;   // exact linspace replication
    *lo = (int)((float)s * step);
    *hi = (int)((float)(s + 1) * step);
}

__device__ __forceinline__ void accum_body(
    const float* __restrict__ frames, float2* __restrict__ ws2,
    int T, int s, int kc, int tid) {
    const int off = landmark_offset(tid);
    int lo, hi;
    seg_bounds(s, T, &lo, &hi);

    float sum = 0.f, sq = 0.f;
    int f = lo + kc;
    for (; f + 7 * NC < hi; f += 8 * NC) {           // 8 independent loads
        float v[8];
#pragma unroll
        for (int u = 0; u < 8; ++u)
            v[u] = frames[(size_t)(f + u * NC) * ROW + off];
#pragma unroll
        for (int u = 0; u < 8; ++u) { sum += v[u]; sq = fmaf(v[u], v[u], sq); }
    }
    for (; f + 3 * NC < hi; f += 4 * NC) {
        float v[4];
#pragma unroll
        for (int u = 0; u < 4; ++u)
            v[u] = frames[(size_t)(f + u * NC) * ROW + off];
#pragma unroll
        for (int u = 0; u < 4; ++u) { sum += v[u]; sq = fmaf(v[u], v[u], sq); }
    }
    for (; f < hi; f += NC) {
        float v = frames[(size_t)f * ROW + off];
        sum += v; sq = fmaf(v, v, sq);
    }

    ws2[kc * NSP + s * N_P + tid] = make_float2(sum, sq);
}

// ---------------- fused kernel: last producer of a segment finalizes it ----
__global__ __launch_bounds__(192) void fused_atomic(
    const float* __restrict__ frames, float2* __restrict__ ws2,
    unsigned* __restrict__ segcnt, float* __restrict__ out, int T) {
    const int bid = blockIdx.x;
    const int tid = threadIdx.x;
    const int s   = bid % N_SEG;   // spreads each segment's producers in time
    const int kc  = bid / N_SEG;

    if (tid < N_P)
        accum_body(frames, ws2, T, s, kc, tid);

    __threadfence();               // release: this thread's partial is visible
    __syncthreads();               // all threads of block have fenced

    __shared__ unsigned old;
    if (tid == 0)
        old = atomicAdd(&segcnt[s], 1u);   // device-scope atomic
    __syncthreads();

    // counter grows by exactly NC per segment per call -> exactly one block
    // per segment per call sees old % NC == NC-1, regardless of poison value.
    if (old % (unsigned)NC == (unsigned)(NC - 1)) {
        __threadfence();           // acquire: see all producers' partials
        if (tid < N_P) {
            const int col = s * N_P + tid;
            float s1 = 0.f, s2 = 0.f;
#pragma unroll 8
            for (int k = 0; k < NC; ++k) {
                float2 v = ws2[k * NSP + col];
                s1 += v.x;
                s2 += v.y;
            }
            int lo, hi;
            seg_bounds(s, T, &lo, &hi);
            const float c = (float)(hi - lo);

            float mean = s1 / c;
            float var  = fmaxf(s2 / c - mean * mean, 0.f);
            float sd   = sqrtf(var);
            if (!(mean == mean)) mean = 0.f;
            if (!(sd == sd))     sd   = 0.f;

            out[s * 328 + tid]       = mean;
            out[s * 328 + 164 + tid] = sd;
        }
    }
}

// ---------------- 2-kernel fallback (proven R6 path) ----------------
__global__ __launch_bounds__(192) void accum_part(
    const float* __restrict__ frames, float2* __restrict__ ws2, int T) {
    if (threadIdx.x >= N_P) return;
    accum_body(frames, ws2, T, blockIdx.x, blockIdx.y, threadIdx.x);
}

__global__ __launch_bounds__(256) void finalize_part(
    const float2* __restrict__ ws2, float* __restrict__ out, int T) {
    const int lane_col = threadIdx.x & (FIN_COLS - 1);
    const int g        = threadIdx.x >> 5;
    const int col      = blockIdx.x * FIN_COLS + lane_col;

    float s1 = 0.f, s2 = 0.f;
#pragma unroll
    for (int k = g * KC_PER_G; k < (g + 1) * KC_PER_G; ++k) {
        float2 v = ws2[k * NSP + col];
        s1 += v.x;
        s2 += v.y;
    }
    __shared__ float ls1[FIN_GROUPS][FIN_COLS];
    __shared__ float ls2[FIN_GROUPS][FIN_COLS];
    ls1[g][lane_col] = s1;
    ls2[g][lane_col] = s2;
    __syncthreads();

    if (g == 0) {
#pragma unroll
        for (int gg = 1; gg < FIN_GROUPS; ++gg) {
            s1 += ls1[gg][lane_col];
            s2 += ls2[gg][lane_col];
        }
        const int s = col / N_P;
        const int p = col % N_P;
        int lo, hi;
        seg_bounds(s, T, &lo, &hi);
        const float c = (float)(hi - lo);

        float mean = s1 / c;
        float var  = fmaxf(s2 / c - mean * mean, 0.f);
        float sd   = sqrtf(var);
        if (!(mean == mean)) mean = 0.f;
        if (!(sd == sd))     sd   = 0.f;

        out[s * 328 + p]       = mean;
        out[s * 328 + 164 + p] = sd;
    }
}

extern "C" void kernel_launch(void* const* d_in, const int* in_sizes, int n_in,
                              void* d_out, int out_size, void* d_ws, size_t ws_size,
                              hipStream_t stream) {
    const float* frames = (const float*)d_in[0];
    float* out = (float*)d_out;
    float2* ws2 = (float2*)d_ws;
    const int T = in_sizes[0] / ROW;   // 32768

    const size_t part_bytes = (size_t)NC * NSP * sizeof(float2);   // ~3.36 MB
    const size_t need = part_bytes + N_SEG * sizeof(unsigned);

    if (ws_size >= need) {
        unsigned* segcnt = (unsigned*)((char*)d_ws + part_bytes);
        fused_atomic<<<NBLK, 192, 0, stream>>>(frames, ws2, segcnt, out, T);
    } else {
        dim3 grid(N_SEG, NC);
        accum_part<<<grid, 192, 0, stream>>>(frames, ws2, T);
        finalize_part<<<NSP / FIN_COLS, 256, 0, stream>>>(ws2, out, T);
    }
}

// Round 9
// 24.235 us; speedup vs baseline: 9.7253x; 9.7253x over previous
//
#include <hip/hip_runtime.h>
#include <hip/hip_bf16.h>

#define N_SEG 64
#define N_L   82              // landmarks (each thread handles x+y)
#define NSL   (N_SEG * N_L)   // 5248
#define ROW   1629            // 543 * 3 floats per frame
#define NC    40              // frame chunks per segment

__device__ __constant__ int LIPS[40] = {
    61, 185, 40, 39, 37, 0, 267, 269, 270, 409, 291, 146, 91, 181, 84, 17,
    314, 405, 321, 375, 78, 191, 80, 81, 82, 13, 312, 311, 310, 415, 95, 88,
    178, 87, 14, 317, 402, 318, 324, 308};

__device__ __forceinline__ int landmark_of(int p) {
    if (p < 21) return 468 + p;          // left hand
    if (p < 42) return 501 + p;          // right hand: 522 + (p-21)
    return LIPS[p - 42];                 // lips
}

__device__ __forceinline__ void seg_bounds(int s, int T, int* lo, int* hi) {
    const float step = (float)(T - 1) / 64.0f;   // exact linspace replication
    *lo = (int)((float)s * step);
    *hi = (int)((float)(s + 1) * step);
}

// ws4[kc * NSL + s*N_L + p] = {sum_x, sum_y, sumsq_x, sumsq_y}
// cnt is analytic (input has no NaNs): per-segment count = hi - lo.
__global__ __launch_bounds__(128) void accum_part(
    const float* __restrict__ frames, float4* __restrict__ ws4, int T) {
    const int s   = blockIdx.x;
    const int kc  = blockIdx.y;
    const int tid = threadIdx.x;
    if (tid >= N_L) return;

    const int off = landmark_of(tid) * 3;   // float offset of x within row
    int lo, hi;
    seg_bounds(s, T, &lo, &hi);

    float sx = 0.f, sy = 0.f, qx = 0.f, qy = 0.f;
    int f = lo + kc;
    for (; f + 7 * NC < hi; f += 8 * NC) {           // 8 independent 8B loads
        float2 v[8];
#pragma unroll
        for (int u = 0; u < 8; ++u)
            v[u] = *reinterpret_cast<const float2*>(
                       &frames[(size_t)(f + u * NC) * ROW + off]);
#pragma unroll
        for (int u = 0; u < 8; ++u) {
            sx += v[u].x; qx = fmaf(v[u].x, v[u].x, qx);
            sy += v[u].y; qy = fmaf(v[u].y, v[u].y, qy);
        }
    }
    for (; f + 3 * NC < hi; f += 4 * NC) {
        float2 v[4];
#pragma unroll
        for (int u = 0; u < 4; ++u)
            v[u] = *reinterpret_cast<const float2*>(
                       &frames[(size_t)(f + u * NC) * ROW + off]);
#pragma unroll
        for (int u = 0; u < 4; ++u) {
            sx += v[u].x; qx = fmaf(v[u].x, v[u].x, qx);
            sy += v[u].y; qy = fmaf(v[u].y, v[u].y, qy);
        }
    }
    for (; f < hi; f += NC) {
        float2 v = *reinterpret_cast<const float2*>(&frames[(size_t)f * ROW + off]);
        sx += v.x; qx = fmaf(v.x, v.x, qx);
        sy += v.y; qy = fmaf(v.y, v.y, qy);
    }

    ws4[kc * NSL + s * N_L + tid] = make_float4(sx, sy, qx, qy);
}

// 41 blocks x 128 threads: one col per thread, coalesced float4 reads
__global__ __launch_bounds__(128) void finalize_part(
    const float4* __restrict__ ws4, float* __restrict__ out, int T) {
    const int col = blockIdx.x * 128 + threadIdx.x;
    if (col >= NSL) return;

    float sx = 0.f, sy = 0.f, qx = 0.f, qy = 0.f;
#pragma unroll 8
    for (int k = 0; k < NC; ++k) {
        float4 v = ws4[k * NSL + col];
        sx += v.x; sy += v.y; qx += v.z; qy += v.w;
    }

    const int s = col / N_L;
    const int p = col % N_L;
    int lo, hi;
    seg_bounds(s, T, &lo, &hi);
    const float c = (float)(hi - lo);

    float mx = sx / c, my = sy / c;
    float vx = fmaxf(qx / c - mx * mx, 0.f);
    float vy = fmaxf(qy / c - my * my, 0.f);
    float dx = sqrtf(vx), dy = sqrtf(vy);
    if (!(mx == mx)) mx = 0.f;
    if (!(my == my)) my = 0.f;
    if (!(dx == dx)) dx = 0.f;
    if (!(dy == dy)) dy = 0.f;

    // out row s: [mean(82,2), std(82,2)] flattened to 328
    float* o = out + s * 328;
    o[2 * p]           = mx;
    o[2 * p + 1]       = my;
    o[164 + 2 * p]     = dx;
    o[164 + 2 * p + 1] = dy;
}

extern "C" void kernel_launch(void* const* d_in, const int* in_sizes, int n_in,
                              void* d_out, int out_size, void* d_ws, size_t ws_size,
                              hipStream_t stream) {
    const float* frames = (const float*)d_in[0];
    float* out = (float*)d_out;
    float4* ws4 = (float4*)d_ws;
    const int T = in_sizes[0] / ROW;   // 32768

    dim3 grid(N_SEG, NC);
    accum_part<<<grid, 128, 0, stream>>>(frames, ws4, T);
    finalize_part<<<(NSL + 127) / 128, 128, 0, stream>>>(ws4, out, T);
}

// Round 10
// 22.941 us; speedup vs baseline: 10.2736x; 1.0564x over previous
//
#include <hip/hip_runtime.h>
#include <hip/hip_bf16.h>

#define N_SEG 64
#define N_P   164             // 82 landmarks * 2 coords
#define NSP   (N_SEG * N_P)   // 10496
#define ROW   1629            // 543 * 3 floats per frame
#define NC    40              // frame chunks per segment
#define MAXF  13              // max frames per thread (ceil(512/40))

#define FIN_COLS   32
#define FIN_GROUPS 8
#define KC_PER_G   (NC / FIN_GROUPS)   // 5

__device__ __constant__ int LIPS[40] = {
    61, 185, 40, 39, 37, 0, 267, 269, 270, 409, 291, 146, 91, 181, 84, 17,
    314, 405, 321, 375, 78, 191, 80, 81, 82, 13, 312, 311, 310, 415, 95, 88,
    178, 87, 14, 317, 402, 318, 324, 308};

__device__ __forceinline__ int landmark_offset(int tid) {
    const int l = tid >> 1;
    const int c = tid & 1;
    int lm;
    if (l < 21)      lm = 468 + l;
    else if (l < 42) lm = 501 + l;           // 522 + (l-21)
    else             lm = LIPS[l - 42];
    return lm * 3 + c;
}

__device__ __forceinline__ void seg_bounds(int s, int T, int* lo, int* hi) {
    const float step = (float)(T - 1) / 64.0f;   // exact linspace replication
    *lo = (int)((float)s * step);
    *hi = (int)((float)(s + 1) * step);
}

// ws2[kc * NSP + s*N_P + p] = {sum, sumsq}; cnt analytic (no NaNs in input)
__global__ __launch_bounds__(192) void accum_part(
    const float* __restrict__ frames, float2* __restrict__ ws2, int T) {
    const int s   = blockIdx.x;
    const int kc  = blockIdx.y;
    const int tid = threadIdx.x;
    if (tid >= N_P) return;

    const int off = landmark_offset(tid);
    int lo, hi;
    seg_bounds(s, T, &lo, &hi);

    const int f0 = lo + kc;
    const int n  = (hi - f0 + NC - 1) / NC;   // block-uniform: 12 or 13

    if (n <= MAXF) {
        // issue ALL loads before consuming any: n outstanding misses/lane
        float v[MAXF];
#pragma unroll
        for (int u = 0; u < MAXF; ++u)
            if (u < n)                         // wave-uniform guard
                v[u] = frames[(size_t)(f0 + u * NC) * ROW + off];

        float sum = 0.f, sq = 0.f;
#pragma unroll
        for (int u = 0; u < MAXF; ++u)
            if (u < n) { sum += v[u]; sq = fmaf(v[u], v[u], sq); }

        ws2[kc * NSP + s * N_P + tid] = make_float2(sum, sq);
    } else {
        // generic fallback (T much larger than expected)
        float sum = 0.f, sq = 0.f;
        for (int f = f0; f < hi; f += NC) {
            float v = frames[(size_t)f * ROW + off];
            sum += v; sq = fmaf(v, v, sq);
        }
        ws2[kc * NSP + s * N_P + tid] = make_float2(sum, sq);
    }
}

// 328 blocks x 256 threads: 32 cols x 8 kc-groups, LDS tree over groups
__global__ __launch_bounds__(256) void finalize_part(
    const float2* __restrict__ ws2, float* __restrict__ out, int T) {
    const int lane_col = threadIdx.x & (FIN_COLS - 1);
    const int g        = threadIdx.x >> 5;
    const int col      = blockIdx.x * FIN_COLS + lane_col;

    float s1 = 0.f, s2 = 0.f;
#pragma unroll
    for (int k = g * KC_PER_G; k < (g + 1) * KC_PER_G; ++k) {
        float2 v = ws2[k * NSP + col];
        s1 += v.x;
        s2 += v.y;
    }
    __shared__ float ls1[FIN_GROUPS][FIN_COLS];
    __shared__ float ls2[FIN_GROUPS][FIN_COLS];
    ls1[g][lane_col] = s1;
    ls2[g][lane_col] = s2;
    __syncthreads();

    if (g == 0) {
#pragma unroll
        for (int gg = 1; gg < FIN_GROUPS; ++gg) {
            s1 += ls1[gg][lane_col];
            s2 += ls2[gg][lane_col];
        }
        const int s = col / N_P;
        const int p = col % N_P;
        int lo, hi;
        seg_bounds(s, T, &lo, &hi);
        const float c = (float)(hi - lo);

        float mean = s1 / c;
        float var  = fmaxf(s2 / c - mean * mean, 0.f);
        float sd   = sqrtf(var);
        if (!(mean == mean)) mean = 0.f;
        if (!(sd == sd))     sd   = 0.f;

        out[s * 328 + p]       = mean;
        out[s * 328 + 164 + p] = sd;
    }
}

extern "C" void kernel_launch(void* const* d_in, const int* in_sizes, int n_in,
                              void* d_out, int out_size, void* d_ws, size_t ws_size,
                              hipStream_t stream) {
    const float* frames = (const float*)d_in[0];
    float* out = (float*)d_out;
    float2* ws2 = (float2*)d_ws;
    const int T = in_sizes[0] / ROW;   // 32768

    dim3 grid(N_SEG, NC);
    accum_part<<<grid, 192, 0, stream>>>(frames, ws2, T);
    finalize_part<<<NSP / FIN_COLS, 256, 0, stream>>>(ws2, out, T);
}